// Round 1
// 561.505 us; speedup vs baseline: 1.0636x; 1.0636x over previous
//
#include <hip/hip_runtime.h>
#include <cstddef>

// GAT multihead layer, MI355X gfx950.  B=4, N=256, H=8, DNI=32, DEI=16, DNO=32, DEO=32.
// Runtime dtype detect (bf16 vs fp32) via k_detect; adj is int32 always.
// d_out = node_new (4*8*256*32) ++ edge_new (4*8*256*256*32) in detected dtype.
//
//  k_detect: sniff W_w bit patterns -> flag in ws
//  k_node:   Wh^T (f-major!), od = nf@Wod^T+b, Whi, Whj -> ws (fp32)
//  k_main:   per (b,i): operand-SWAPPED MFMA edge GEMM (D transposed so each lane owns
//            4 consecutive features -> f32x4 epilogue), XOR-swizzled 32KB LDS tile
//            (40KB total -> 4 blocks/CU), nt stores; softmax; node row via whT f32x4.

typedef __attribute__((ext_vector_type(8))) short short8;
typedef __attribute__((ext_vector_type(4))) short short4v;
typedef __attribute__((ext_vector_type(4))) float f32x4;

__device__ __forceinline__ float bf2f(unsigned short u) {
  union { unsigned int i; float f; } c;
  c.i = ((unsigned int)u) << 16;
  return c.f;
}
__device__ __forceinline__ unsigned short f2bf(float f) {
  union { float f; unsigned int i; } c; c.f = f;
  unsigned int x = c.i;
  x += 0x7fffu + ((x >> 16) & 1u);   // RNE
  return (unsigned short)(x >> 16);
}

struct F8 { f32x4 lo, hi; };

__device__ __forceinline__ float loadf(const void* p, size_t i, bool bf) {
  return bf ? bf2f(((const unsigned short*)p)[i]) : ((const float*)p)[i];
}
__device__ __forceinline__ f32x4 load4f(const void* p, size_t i, bool bf) {
  f32x4 r;
  if (bf) {
    #pragma unroll
    for (int k = 0; k < 4; k++) r[k] = bf2f(((const unsigned short*)p)[i + k]);
  } else {
    r = *(const f32x4*)((const float*)p + i);
  }
  return r;
}
__device__ __forceinline__ F8 load8f(const void* p, size_t i, bool bf) {
  F8 r;
  if (bf) {
    short8 s = *(const short8*)((const unsigned short*)p + i);
    #pragma unroll
    for (int k = 0; k < 4; k++) {
      r.lo[k] = bf2f((unsigned short)s[k]);
      r.hi[k] = bf2f((unsigned short)s[k + 4]);
    }
  } else {
    const float* f = (const float*)p + i;
    r.lo = *(const f32x4*)f;
    r.hi = *(const f32x4*)(f + 4);
  }
  return r;
}
__device__ __forceinline__ short8 load8bf(const void* p, size_t i, bool bf) {
  if (bf) return *(const short8*)((const unsigned short*)p + i);
  const float* f = (const float*)p + i;
  f32x4 a = *(const f32x4*)f, c = *(const f32x4*)(f + 4);
  short8 r;
  #pragma unroll
  for (int k = 0; k < 4; k++) {
    r[k]     = (short)f2bf(a[k]);
    r[k + 4] = (short)f2bf(c[k]);
  }
  return r;
}
__device__ __forceinline__ void storef(void* p, size_t i, float v, bool bf) {
  if (bf) ((unsigned short*)p)[i] = f2bf(v);
  else    ((float*)p)[i] = v;
}

// ---------------------------------------------------------------- k_detect
__global__ void k_detect(const unsigned int* __restrict__ w, int* __restrict__ flag) {
  const int lane = threadIdx.x;
  unsigned int x = w[lane];
  unsigned int e = (x >> 7) & 0xFFu;
  bool hit = (e >= 100u && e <= 126u);
  unsigned long long b = __ballot(hit);
  if (lane == 0) *flag = (__popcll(b) >= 32) ? 1 : 0;
}

// ---------------------------------------------------------------- k_node
// grid 512 (2 rows/block), block 256. Thread t = output feature o (0..255). fp32 math.
// Wh is written TRANSPOSED: whT[b][f][j] (f-major) for the k_main node phase.
__global__ __launch_bounds__(256) void k_node(
    const void* __restrict__ node_fea,
    const void* __restrict__ W_w,  const void* __restrict__ W_b,
    const void* __restrict__ a1_w, const void* __restrict__ a2_w,
    const void* __restrict__ Wod_w, const void* __restrict__ Wod_b,
    const int* __restrict__ flag,
    float* __restrict__ whT, float* __restrict__ od,
    float* __restrict__ whi, float* __restrict__ whj)
{
  const bool bf = (*flag != 0);
  __shared__ float nf[2][256];
  __shared__ float red[4][32];
  const int t = threadIdx.x;
  const int row0 = blockIdx.x * 2;          // global row = b*256+n
  const int b = row0 >> 8;
  {
    const int rl = t >> 7, k2 = (t & 127) * 2;
    const int h = k2 >> 5, d = k2 & 31;
    const int n = (row0 & 255) + rl;
    const size_t idx = (((size_t)(b * 8 + h)) * 256 + n) * 32 + d;
    nf[rl][k2]     = loadf(node_fea, idx, bf);
    nf[rl][k2 + 1] = loadf(node_fea, idx + 1, bf);
  }
  __syncthreads();
  const int o = t;
  float acc1[2] = {0.f, 0.f}, acc2[2] = {0.f, 0.f};
  #pragma unroll 4
  for (int kc = 0; kc < 32; kc++) {
    F8 w1 = load8f(W_w,   (size_t)o * 256 + kc * 8, bf);
    F8 w2 = load8f(Wod_w, (size_t)o * 256 + kc * 8, bf);
    #pragma unroll
    for (int r = 0; r < 2; r++) {
      f32x4 alo = *(const f32x4*)&nf[r][kc * 8];
      f32x4 ahi = *(const f32x4*)&nf[r][kc * 8 + 4];
      #pragma unroll
      for (int k = 0; k < 4; k++) {
        acc1[r] += alo[k] * w1.lo[k] + ahi[k] * w1.hi[k];
        acc2[r] += alo[k] * w2.lo[k] + ahi[k] * w2.hi[k];
      }
    }
  }
  float whv[2], odv[2];
  {
    float b1 = loadf(W_b, o, bf), b2 = loadf(Wod_b, o, bf);
    #pragma unroll
    for (int r = 0; r < 2; r++) {
      whv[r] = acc1[r] + b1;
      odv[r] = acc2[r] + b2;
      whT[(((size_t)(b * 256 + o)) << 8) + (row0 & 255) + r] = whv[r];
      od[(size_t)(row0 + r) * 256 + o] = odv[r];
    }
  }
  float a1f[8], a2f[8];
  #pragma unroll
  for (int h = 0; h < 8; h++) {
    a1f[h] = loadf(a1_w, (size_t)h * 256 + o, bf);
    a2f[h] = loadf(a2_w, (size_t)h * 256 + o, bf);
  }
  const int lane = t & 63, wv = t >> 6;
  #pragma unroll 1
  for (int c = 0; c < 32; c++) {
    const int mat = c >> 4, r = (c >> 3) & 1, h = c & 7;
    float v = whv[r] * (mat ? a2f[h] : a1f[h]);
    #pragma unroll
    for (int s = 1; s < 64; s <<= 1) v += __shfl_xor(v, s, 64);
    if (lane == 0) red[wv][c] = v;
  }
  __syncthreads();
  if (t < 32) {
    const int c = t;
    float s = red[0][c] + red[1][c] + red[2][c] + red[3][c];
    const int mat = c >> 4, r = (c >> 3) & 1, h = c & 7;
    (mat ? whj : whi)[(size_t)(row0 + r) * 8 + h] = s;
  }
}

// ---------------------------------------------------------------- k_main
// grid 1024 = b(4) x i(256), block 256 (4 waves). LDS = 32KB tile + 8KB logits = 40KB
// -> 4 blocks/CU. MFMA operands SWAPPED: D' = We_frag * ef_frag, so lane (quad,col)
// holds D'[f = nt*16 + quad*4 + r][j = mt*16 + col] -> f32x4 epilogue per lane.
__global__ __launch_bounds__(256, 4) void k_main(
    const void* __restrict__ edge_fea, const int* __restrict__ adj,
    const void* __restrict__ ae_w, const void* __restrict__ ae_b,
    const void* __restrict__ We_w, const void* __restrict__ We_b,
    const int* __restrict__ flag,
    const float* __restrict__ od, const float* __restrict__ whi,
    const float* __restrict__ whj, const float* __restrict__ whT,
    void* __restrict__ out)            // out_node at elem 0, out_edge at elem 262144
{
  const bool bf = (*flag != 0);
  // A: 128 rows x 128 bf16, row = 256B = 16 slots of 16B, slot XOR-swizzled by (row&7).
  __shared__ unsigned short A[16384];      // 32 KB
  __shared__ float e_l[8][256];            // logits -> att, 8 KB
  const int t = threadIdx.x;
  const int blk = blockIdx.x;
  const int i = blk & 255, b = blk >> 8;
  const int wave = t >> 6, lane = t & 63, quad = lane >> 4, col = lane & 15;

  // loop-invariant We fragments: lane holds We[n = (wave*4+s)*16+col][k = ks*32+quad*8+..]
  // (used as FIRST mfma operand -> its n becomes the D row -> f in registers)
  short8 bw[4][4];
  #pragma unroll
  for (int s = 0; s < 4; s++) {
    const int n = (wave * 4 + s) * 16 + col;
    #pragma unroll
    for (int ks = 0; ks < 4; ks++)
      bw[s][ks] = load8bf(We_w, (size_t)n * 128 + ks * 32 + quad * 8, bf);
  }

  // per-lane epilogue constants: f0 = (wave*4+s)*16 + quad*4, 4 consecutive features
  f32x4 ow4[4];
  #pragma unroll
  for (int s = 0; s < 4; s++) {
    const int f0 = (wave * 4 + s) * 16 + quad * 4;
    f32x4 oi = *(const f32x4*)(od + (((size_t)(b * 256 + i)) << 8) + f0);
    f32x4 wb = load4f(We_b, f0, bf);
    ow4[s] = oi + wb;
  }

  // ---- edge GEMM over both j-halves
  #pragma unroll 1
  for (int jt = 0; jt < 2; jt++) {
    const int j0 = jt * 128;
    {
      const int jr = t >> 1, e8 = (t & 1) * 8;
      unsigned short* arow = &A[jr * 128];
      const int sx = jr & 7;
      #pragma unroll
      for (int h = 0; h < 8; h++) {
        const size_t idx = ((((size_t)(b * 8 + h)) * 256 + i) * 256 + j0 + jr) * 16 + e8;
        const int slot = (h * 2 + (e8 >> 3)) ^ sx;
        *(short8*)(arow + slot * 8) = load8bf(edge_fea, idx, bf);
      }
    }
    __syncthreads();

    #pragma unroll 1
    for (int mt = 0; mt < 8; mt++) {
      const int row = mt * 16 + col;
      const unsigned short* arow = &A[row * 128];
      const int rx = row & 7;
      f32x4 acc[4];
      #pragma unroll
      for (int s = 0; s < 4; s++) acc[s] = (f32x4){0.f, 0.f, 0.f, 0.f};
      #pragma unroll
      for (int ks = 0; ks < 4; ks++) {
        short8 a = *(const short8*)(arow + ((ks * 4 + quad) ^ rx) * 8);
        acc[0] = __builtin_amdgcn_mfma_f32_16x16x32_bf16(bw[0][ks], a, acc[0], 0, 0, 0);
        acc[1] = __builtin_amdgcn_mfma_f32_16x16x32_bf16(bw[1][ks], a, acc[1], 0, 0, 0);
        acc[2] = __builtin_amdgcn_mfma_f32_16x16x32_bf16(bw[2][ks], a, acc[2], 0, 0, 0);
        acc[3] = __builtin_amdgcn_mfma_f32_16x16x32_bf16(bw[3][ks], a, acc[3], 0, 0, 0);
      }
      // D' layout: lane holds D'[f = (wave*4+s)*16+quad*4 + r][j = mt*16+col]
      const int j = j0 + mt * 16 + col;
      const float* odj = od + (((size_t)(b * 256 + j)) << 8);
      #pragma unroll
      for (int s = 0; s < 4; s++) {
        const int f0 = (wave * 4 + s) * 16 + quad * 4;
        const int h = f0 >> 5, d0 = f0 & 31;
        f32x4 op = *(const f32x4*)(odj + f0);
        f32x4 v = acc[s] + ow4[s] + op;
        const size_t oidx =
            262144 + (((((size_t)(b * 8 + h)) * 256 + i) * 256 + j) * 32 + d0);
        if (bf) {
          short4v sv;
          #pragma unroll
          for (int r = 0; r < 4; r++) sv[r] = (short)f2bf(v[r]);
          __builtin_nontemporal_store(sv, (short4v*)((unsigned short*)out + oidx));
        } else {
          __builtin_nontemporal_store(v, (f32x4*)((float*)out + oidx));
        }
      }
    }

    // ---- attention logits for this j-half: wave handles mt = wave*2 + mm
    {
      short8 bae[4];
      #pragma unroll
      for (int ks = 0; ks < 4; ks++) {
        short8 z = {0, 0, 0, 0, 0, 0, 0, 0};
        bae[ks] = (col < 8) ? load8bf(ae_w, (size_t)col * 128 + ks * 32 + quad * 8, bf) : z;
      }
      f32x4 whi4 = {0.f, 0.f, 0.f, 0.f}, aeb4 = {0.f, 0.f, 0.f, 0.f};
      if (quad < 2) {
        whi4 = *(const f32x4*)(whi + ((size_t)(b * 256 + i)) * 8 + quad * 4);
        aeb4 = load4f(ae_b, quad * 4, bf);
      }
      #pragma unroll
      for (int mm = 0; mm < 2; mm++) {
        const int mt = wave * 2 + mm;
        const int row = mt * 16 + col;
        const unsigned short* arow = &A[row * 128];
        const int rx = row & 7;
        f32x4 acce = {0.f, 0.f, 0.f, 0.f};
        #pragma unroll
        for (int ks = 0; ks < 4; ks++) {
          short8 a = *(const short8*)(arow + ((ks * 4 + quad) ^ rx) * 8);
          acce = __builtin_amdgcn_mfma_f32_16x16x32_bf16(bae[ks], a, acce, 0, 0, 0);
        }
        // D'' layout: lane (quad<2) holds e_edge[h = quad*4+r][j = mt*16+col]
        if (quad < 2) {
          const int j = j0 + mt * 16 + col;
          f32x4 wj = *(const f32x4*)(whj + ((size_t)(b * 256 + j)) * 8 + quad * 4);
          const int av = adj[((size_t)(b * 256 + i)) * 256 + j];
          #pragma unroll
          for (int r = 0; r < 4; r++) {
            float e = acce[r] + aeb4[r] + whi4[r] + wj[r];
            e = (e > 0.f) ? e : 0.2f * e;
            e = (av > 0) ? e : -9e15f;
            e_l[quad * 4 + r][j] = e;     // bank = j%32 -> 2-way max (free)
          }
        }
      }
    }
    __syncthreads();   // A reads done (next jt restages); after jt=1: e_l complete
  }

  // ---- softmax over j, per head row. t -> (h = t>>5, l32 = t&31)
  {
    const int h = t >> 5, l32 = t & 31;
    float m = -3.0e38f;
    #pragma unroll
    for (int k = 0; k < 8; k++) m = fmaxf(m, e_l[h][l32 + 32 * k]);
    #pragma unroll
    for (int s = 16; s >= 1; s >>= 1) m = fmaxf(m, __shfl_xor(m, s, 32));
    float p[8], sum = 0.f;
    #pragma unroll
    for (int k = 0; k < 8; k++) {
      p[k] = __expf(e_l[h][l32 + 32 * k] - m);
      sum += p[k];
    }
    #pragma unroll
    for (int s = 16; s >= 1; s >>= 1) sum += __shfl_xor(sum, s, 32);
    const float inv = 1.0f / sum;      // sum >= 1 (max element contributes exp(0)=1)
    #pragma unroll
    for (int k = 0; k < 8; k++) e_l[h][l32 + 32 * k] = p[k] * inv;
  }
  __syncthreads();

  // ---- node_new[b, h, i, d] = sum_j att[h][j]*Wh[b,j,f] + Wh[b,i,f],  f = t = h*32+d
  // whT is f-major: row f = 256 consecutive j -> f32x4 loads with L1 locality.
  {
    const int h = t >> 5;
    const float* wr = whT + (((size_t)(b * 256 + t)) << 8);
    f32x4 a4 = {0.f, 0.f, 0.f, 0.f};
    #pragma unroll 8
    for (int j4 = 0; j4 < 64; j4++) {
      f32x4 w4 = *(const f32x4*)(wr + j4 * 4);
      const f32x4 p4 = *(const f32x4*)&e_l[h][j4 * 4];
      a4 += w4 * p4;
    }
    float v = (a4[0] + a4[1]) + (a4[2] + a4[3]) + wr[i];
    const size_t oe = (((size_t)(b * 8 + h)) * 256 + i) * 32 + (t & 31);
    storef(out, oe, v, bf);
  }
}

// ---------------------------------------------------------------- launch
extern "C" void kernel_launch(void* const* d_in, const int* in_sizes, int n_in,
                              void* d_out, int out_size, void* d_ws, size_t ws_size,
                              hipStream_t stream) {
  const void* node_fea = d_in[0];
  const void* edge_fea = d_in[1];
  const int*  adj      = (const int*)d_in[2];
  const void* W_w      = d_in[3];
  const void* W_b      = d_in[4];
  const void* a1_w     = d_in[5];
  const void* a2_w     = d_in[6];
  const void* ae_w     = d_in[7];
  const void* ae_b     = d_in[8];
  const void* We_w     = d_in[9];
  const void* We_b     = d_in[10];
  const void* Wod_w    = d_in[11];
  const void* Wod_b    = d_in[12];

  int*   flag = (int*)d_ws;
  float* base = (float*)d_ws;
  float* whT  = base + 16;          // [4*256 f][256 j]
  float* od   = whT + 262144;       // [1024][256]
  float* whi  = od + 262144;        // [1024][8]
  float* whj  = whi + 8192;         // [1024][8]
                                    // total ~2.16 MB of ws

  k_detect<<<dim3(1), dim3(64), 0, stream>>>((const unsigned int*)W_w, flag);
  k_node<<<dim3(512), dim3(256), 0, stream>>>(node_fea, W_w, W_b, a1_w, a2_w,
                                              Wod_w, Wod_b, flag, whT, od, whi, whj);
  k_main<<<dim3(1024), dim3(256), 0, stream>>>(edge_fea, adj, ae_w, ae_b, We_w, We_b,
                                               flag, od, whi, whj, whT, d_out);
}